// Round 1
// baseline (38508.881 us; speedup 1.0000x reference)
//
#include <hip/hip_runtime.h>
#include <math.h>

// ---------------------------------------------------------------------------
// 4-layer LSTM stack, B=64 T=512 D=H=1024. Persistent cooperative kernel.
// Wavefront schedule: step s in [0, T+L-1): layer l processes t = s - l.
// All GEMMs via v_mfma_f32_16x16x32_f16 (fp16 inputs, fp32 accumulate).
// c-state, gate nonlinearities, output: fp32.
// Grid: 256 blocks = L(4) x 64 col-chunks (16 H-cols each); 4 waves/block,
// wave g computes gate g's [64 batch x 16 col] z-slice over K=1024, for both
// the input-side matrix (x_t or h_{l-1,t}) and the recurrent matrix (h_{l,t-1}).
// Activations staged through LDS in K-chunks of 128 and shared by the 4 waves;
// weight rows are read straight from global (L3-resident after step 0), each
// weight byte exactly once per step.
// ---------------------------------------------------------------------------

#define BSZ 64
#define TSZ 512
#define DSZ 1024
#define HSZ 1024
#define LSZ 4
#define NBLK 256
#define NTHR 256
#define NSTEP (TSZ + LSZ - 1)   // 515

typedef _Float16 half8 __attribute__((ext_vector_type(8)));
typedef _Float16 half4 __attribute__((ext_vector_type(4)));
typedef float    f32x4 __attribute__((ext_vector_type(4)));

// workspace layout (bytes)
constexpr size_t N_W  = (size_t)LSZ * 4 * HSZ * DSZ;   // 16,777,216 elems per W tensor
constexpr size_t N_X  = (size_t)BSZ * TSZ * DSZ;       // 33,554,432
constexpr size_t N_H  = (size_t)2 * LSZ * BSZ * HSZ;   // 524,288 (double-buffered h, fp16)
constexpr size_t N_C  = (size_t)LSZ * BSZ * HSZ;       // 262,144 (c state, fp32)
constexpr size_t OFF_WIH = 0;
constexpr size_t OFF_WHH = OFF_WIH + N_W * 2;
constexpr size_t OFF_X   = OFF_WHH + N_W * 2;
constexpr size_t OFF_H   = OFF_X + N_X * 2;
constexpr size_t OFF_C   = OFF_H + N_H * 2;
constexpr size_t OFF_BAR = OFF_C + N_C * 4;            // 136,314,880

__device__ inline float sigmoidf_(float x) { return 1.0f / (1.0f + expf(-x)); }

// generation-counter grid barrier (device-scope acq/rel; blocks co-resident
// via cooperative launch)
__device__ inline void grid_barrier(unsigned* cnt, unsigned* gen) {
  __syncthreads();
  if (threadIdx.x == 0) {
    __threadfence();
    unsigned g = __hip_atomic_load(gen, __ATOMIC_RELAXED, __HIP_MEMORY_SCOPE_AGENT);
    unsigned arrived =
        __hip_atomic_fetch_add(cnt, 1u, __ATOMIC_ACQ_REL, __HIP_MEMORY_SCOPE_AGENT);
    if (arrived == NBLK - 1) {
      __hip_atomic_store(cnt, 0u, __ATOMIC_RELAXED, __HIP_MEMORY_SCOPE_AGENT);
      __hip_atomic_store(gen, g + 1u, __ATOMIC_RELEASE, __HIP_MEMORY_SCOPE_AGENT);
    } else {
      while (__hip_atomic_load(gen, __ATOMIC_ACQUIRE, __HIP_MEMORY_SCOPE_AGENT) == g) {
        __builtin_amdgcn_s_sleep(2);
      }
    }
  }
  __syncthreads();
}

__global__ __launch_bounds__(NTHR) void lstm_persistent(
    const float* __restrict__ xin, const float* __restrict__ Wih,
    const float* __restrict__ Whh, const float* __restrict__ bih,
    const float* __restrict__ bhh, float* __restrict__ out,
    char* __restrict__ ws)
{
  _Float16* Wih16 = (_Float16*)(ws + OFF_WIH);
  _Float16* Whh16 = (_Float16*)(ws + OFF_WHH);
  _Float16* x16   = (_Float16*)(ws + OFF_X);
  _Float16* h16   = (_Float16*)(ws + OFF_H);
  float*    c32   = (float*)   (ws + OFF_C);
  unsigned* bar   = (unsigned*)(ws + OFF_BAR);

  const int tid  = threadIdx.x;
  const int gtid = blockIdx.x * NTHR + tid;

  // ---- pre-phase: fp32->fp16 casts + zero-init of h/c (every call) ----
  {
    const f32x4* s4 = (const f32x4*)Wih;
    half4*       d4 = (half4*)Wih16;
    for (int i = gtid; i < (int)(N_W / 4); i += NBLK * NTHR)
      d4[i] = __builtin_convertvector(s4[i], half4);
    s4 = (const f32x4*)Whh; d4 = (half4*)Whh16;
    for (int i = gtid; i < (int)(N_W / 4); i += NBLK * NTHR)
      d4[i] = __builtin_convertvector(s4[i], half4);
    s4 = (const f32x4*)xin; d4 = (half4*)x16;
    for (int i = gtid; i < (int)(N_X / 4); i += NBLK * NTHR)
      d4[i] = __builtin_convertvector(s4[i], half4);
    f32x4 zz = {0.f, 0.f, 0.f, 0.f};
    f32x4* hz = (f32x4*)h16;                    // N_H halfs = N_H/8 f32x4
    for (int i = gtid; i < (int)(N_H / 8); i += NBLK * NTHR) hz[i] = zz;
    f32x4* cz = (f32x4*)c32;
    for (int i = gtid; i < (int)(N_C / 4); i += NBLK * NTHR) cz[i] = zz;
  }
  grid_barrier(bar, bar + 1);

  // ---- static block role ----
  const int l    = blockIdx.x >> 6;        // layer 0..3
  const int cc   = blockIdx.x & 63;        // column chunk
  const int c0   = cc * 16;                // H-column base
  const int lane = tid & 63;
  const int g    = tid >> 6;               // gate 0..3 (i,f,g,o)
  const int ln15 = lane & 15;
  const int lq   = lane >> 4;

  const _Float16* wih_row =
      Wih16 + ((size_t)(l * 4 * HSZ + g * HSZ + c0 + ln15)) * DSZ;
  const _Float16* whh_row =
      Whh16 + ((size_t)(l * 4 * HSZ + g * HSZ + c0 + ln15)) * HSZ;

  // LDS: K-chunk of both activation matrices, padded to 136 halfs/row
  // (row stride 272B -> 2-way bank aliasing only). + z exchange buffer.
  __shared__ _Float16 lds_a[2][64][136];   // 34,816 B
  __shared__ float    zbuf[4][64][16];     // 16,384 B  (total 51,200 < 64K)

  const int lm1 = (l > 0) ? (l - 1) : 0;

  for (int s = 0; s < NSTEP; ++s) {
    const int t = s - l;
    if (t >= 0 && t < TSZ) {
      const int prevslot = (s + 1) & 1;
      const _Float16* hprev_in =
          h16 + (size_t)prevslot * (LSZ * BSZ * HSZ) + (size_t)lm1 * (BSZ * HSZ);
      const _Float16* hprev_own =
          h16 + (size_t)prevslot * (LSZ * BSZ * HSZ) + (size_t)l * (BSZ * HSZ);

      f32x4 acc[4] = {};

      for (int kc = 0; kc < 8; ++kc) {       // K chunks of 128
        const int kbase = kc * 128;
        // stage both activation matrices' chunk into LDS (coalesced 16B)
        for (int it = 0; it < 8; ++it) {
          int idx8 = tid + it * NTHR;        // 0..2047 half8-slots
          int mat  = idx8 >> 10;
          int rem  = idx8 & 1023;
          int row  = rem >> 4;               // batch 0..63
          int kl   = (rem & 15) * 8;
          const _Float16* src;
          if (mat == 0) {
            src = (l == 0)
                      ? (x16 + ((size_t)row * TSZ + t) * DSZ + kbase + kl)
                      : (hprev_in + (size_t)row * HSZ + kbase + kl);
          } else {
            src = hprev_own + (size_t)row * HSZ + kbase + kl;
          }
          *(half8*)&lds_a[mat][row][kl] = *(const half8*)src;
        }
        __syncthreads();

#pragma unroll
        for (int ks = 0; ks < 4; ++ks) {     // 4 k-steps of 32 per chunk
          const int kl    = ks * 32 + lq * 8;
          const int kglob = kbase + kl;
          half8 b0 = *(const half8*)(wih_row + kglob);
          half8 b1 = *(const half8*)(whh_row + kglob);
          half8 a0[4], a1[4];
#pragma unroll
          for (int mt = 0; mt < 4; ++mt) {
            a0[mt] = *(const half8*)&lds_a[0][mt * 16 + ln15][kl];
            a1[mt] = *(const half8*)&lds_a[1][mt * 16 + ln15][kl];
          }
#pragma unroll
          for (int mt = 0; mt < 4; ++mt)
            acc[mt] = __builtin_amdgcn_mfma_f32_16x16x32_f16(a0[mt], b0, acc[mt], 0, 0, 0);
#pragma unroll
          for (int mt = 0; mt < 4; ++mt)
            acc[mt] = __builtin_amdgcn_mfma_f32_16x16x32_f16(a1[mt], b1, acc[mt], 0, 0, 0);
        }
        __syncthreads();
      }

      // exchange z across the 4 gate-waves
#pragma unroll
      for (int mt = 0; mt < 4; ++mt)
#pragma unroll
        for (int r = 0; r < 4; ++r)
          zbuf[g][mt * 16 + lq * 4 + r][ln15] = acc[mt][r];
      __syncthreads();

      // gate nonlinearities + state update (fp32)
      for (int e = tid; e < BSZ * 16; e += NTHR) {
        int b    = e >> 4;
        int col  = e & 15;
        int cidx = c0 + col;
        int bb   = l * 4 * HSZ + cidx;
        float zi = zbuf[0][b][col] + bih[bb + 0 * HSZ] + bhh[bb + 0 * HSZ];
        float zf = zbuf[1][b][col] + bih[bb + 1 * HSZ] + bhh[bb + 1 * HSZ];
        float zg = zbuf[2][b][col] + bih[bb + 2 * HSZ] + bhh[bb + 2 * HSZ];
        float zo = zbuf[3][b][col] + bih[bb + 3 * HSZ] + bhh[bb + 3 * HSZ];
        size_t ci = (size_t)l * (BSZ * HSZ) + (size_t)b * HSZ + cidx;
        float cold = c32[ci];
        float cn = sigmoidf_(zf) * cold + sigmoidf_(zi) * tanhf(zg);
        float hn = sigmoidf_(zo) * tanhf(cn);
        c32[ci] = cn;
        h16[(size_t)(s & 1) * (LSZ * BSZ * HSZ) + (size_t)l * (BSZ * HSZ) +
            (size_t)b * HSZ + cidx] = (_Float16)hn;
        if (l == LSZ - 1) out[(size_t)b * HSZ + cidx] = hn;
      }
    }
    grid_barrier(bar, bar + 1);
  }
}

extern "C" void kernel_launch(void* const* d_in, const int* in_sizes, int n_in,
                              void* d_out, int out_size, void* d_ws, size_t ws_size,
                              hipStream_t stream) {
  const float* x   = (const float*)d_in[0];
  const float* Wih = (const float*)d_in[1];
  const float* Whh = (const float*)d_in[2];
  const float* bih = (const float*)d_in[3];
  const float* bhh = (const float*)d_in[4];
  float* out = (float*)d_out;
  char*  ws  = (char*)d_ws;

  // barrier state must be zeroed every call (ws is poisoned once to 0xAA)
  hipMemsetAsync(ws + OFF_BAR, 0, 256, stream);

  void* args[] = {(void*)&x, (void*)&Wih, (void*)&Whh, (void*)&bih,
                  (void*)&bhh, (void*)&out, (void*)&ws};
  hipLaunchCooperativeKernel((const void*)lstm_persistent, dim3(NBLK), dim3(NTHR),
                             args, 0, stream);
}

// Round 3
// 25561.703 us; speedup vs baseline: 1.5065x; 1.5065x over previous
//
#include <hip/hip_runtime.h>
#include <math.h>

// ---------------------------------------------------------------------------
// 4-layer LSTM, B=64 T=512 D=H=1024. Persistent cooperative kernel, wavefront
// schedule (layer l works on t = s - l). Round-3 structure:
//   - Weights in VGPRs for the whole kernel. 8 waves/block (512 thr):
//     wave (mat, rt) holds gate rt's 16 rows of matrix mat as bw[32] half8
//     (128 VGPR). No per-step weight memory traffic.
//   - Activations staged via registers + ds_write_b128 (NO global_load_lds),
//     double-buffered K-chunks of 64, XOR bank swizzle (byte ^= (row&7)<<4)
//     applied identically on LDS write and read.
//   - LDS total 34816 B (2 x 16 KB bufs + overlaid f32 zbuf[2][64][68]).
//   - mat0/mat1 partials summed via zbuf, fp32 gate math, one grid barrier
//     per step (round-1-verified barrier).
// ---------------------------------------------------------------------------

#define BSZ 64
#define TSZ 512
#define DSZ 1024
#define HSZ 1024
#define LSZ 4
#define NBLK 256
#define NTHR 512
#define NSTEP (TSZ + LSZ - 1)   // 515
#define BUFB 16384               // bytes per activation buffer

typedef _Float16 half8 __attribute__((ext_vector_type(8)));
typedef _Float16 half4 __attribute__((ext_vector_type(4)));
typedef float    f32x4 __attribute__((ext_vector_type(4)));
typedef float    f32x8 __attribute__((ext_vector_type(8)));

// workspace layout (bytes)
constexpr size_t N_X  = (size_t)BSZ * TSZ * DSZ;       // halfs
constexpr size_t N_H  = (size_t)2 * LSZ * BSZ * HSZ;   // halfs (double-buffered h)
constexpr size_t N_C  = (size_t)LSZ * BSZ * HSZ;       // floats (c state)
constexpr size_t OFF_X   = 0;
constexpr size_t OFF_H   = OFF_X + N_X * 2;
constexpr size_t OFF_C   = OFF_H + N_H * 2;
constexpr size_t OFF_BAR = OFF_C + N_C * 4;

__device__ inline float sigmoidf_(float x) { return 1.0f / (1.0f + expf(-x)); }

__device__ inline void grid_barrier(unsigned* cnt, unsigned* gen) {
  __syncthreads();
  if (threadIdx.x == 0) {
    __threadfence();
    unsigned g = __hip_atomic_load(gen, __ATOMIC_RELAXED, __HIP_MEMORY_SCOPE_AGENT);
    unsigned arrived =
        __hip_atomic_fetch_add(cnt, 1u, __ATOMIC_ACQ_REL, __HIP_MEMORY_SCOPE_AGENT);
    if (arrived == NBLK - 1) {
      __hip_atomic_store(cnt, 0u, __ATOMIC_RELAXED, __HIP_MEMORY_SCOPE_AGENT);
      __hip_atomic_store(gen, g + 1u, __ATOMIC_RELEASE, __HIP_MEMORY_SCOPE_AGENT);
    } else {
      while (__hip_atomic_load(gen, __ATOMIC_ACQUIRE, __HIP_MEMORY_SCOPE_AGENT) == g) {
        __builtin_amdgcn_s_sleep(2);
      }
    }
  }
  __syncthreads();
}

__global__ __launch_bounds__(NTHR, 2) void lstm_persistent(
    const float* __restrict__ xin, const float* __restrict__ Wih,
    const float* __restrict__ Whh, const float* __restrict__ bih,
    const float* __restrict__ bhh, float* __restrict__ out,
    char* __restrict__ ws)
{
  _Float16* x16 = (_Float16*)(ws + OFF_X);
  _Float16* h16 = (_Float16*)(ws + OFF_H);
  float*    c32 = (float*)   (ws + OFF_C);
  unsigned* bar = (unsigned*)(ws + OFF_BAR);

  const int tid  = threadIdx.x;
  const int gtid = blockIdx.x * NTHR + tid;
  const int lane = tid & 63;
  const int w    = tid >> 6;        // wave 0..7
  const int mat  = w >> 2;          // 0 = input-side, 1 = recurrent
  const int rt   = w & 3;           // gate (row-tile of 16 weight rows)
  const int ln15 = lane & 15;
  const int lq   = lane >> 4;

  const int l  = blockIdx.x >> 6;   // layer
  const int cc = blockIdx.x & 63;   // column chunk (16 H-cols)
  const int c0 = cc * 16;

  // ---- weight preload into registers (fp32 -> fp16, one time) ----
  // B-frag convention (round-1-verified): lane ln15 holds weight row
  // (gate rt, col c0+ln15); k = ks*32 + lq*8 + 0..7.
  const float* Wsel = mat ? Whh : Wih;
  half8 bw[32];
  {
    const int grow = l * 4096 + rt * 1024 + c0 + ln15;
    const float* wrow = Wsel + (size_t)grow * 1024;
#pragma unroll
    for (int ks = 0; ks < 32; ++ks) {
      f32x8 f = *(const f32x8*)(wrow + ks * 32 + lq * 8);
      bw[ks] = __builtin_convertvector(f, half8);
    }
  }

  // ---- pre-phase: cast x to fp16, zero h (both slots) and c ----
  {
    const f32x4* s4 = (const f32x4*)xin;
    half4*       d4 = (half4*)x16;
    for (int i = gtid; i < (int)(N_X / 4); i += NBLK * NTHR)
      d4[i] = __builtin_convertvector(s4[i], half4);
    f32x4 zz = {0.f, 0.f, 0.f, 0.f};
    f32x4* hz = (f32x4*)h16;
    for (int i = gtid; i < (int)(N_H / 8); i += NBLK * NTHR) hz[i] = zz;
    f32x4* cz = (f32x4*)c32;
    for (int i = gtid; i < (int)(N_C / 4); i += NBLK * NTHR) cz[i] = zz;
  }
  grid_barrier(bar, bar + 1);

  // ---- LDS: 2 activation buffers (16 KB each) + overlaid zbuf ----
  // buf k at smem + k*BUFB: [2 mats][64 rows][64 halfs(128B)], XOR-swizzled.
  // zbuf f32[2][64][68] (34816 B) overlays everything after final compute.
  __shared__ __align__(16) char smem[34816];
  float* zb = (float*)smem;

  const int lm1 = (l > 0) ? (l - 1) : 0;

  for (int s = 0; s < NSTEP; ++s) {
    const int t = s - l;
    if (t >= 0 && t < TSZ) {
      const int prevslot = (s + 1) & 1;
      const _Float16* hin  = h16 + (size_t)prevslot * (LSZ * BSZ * HSZ) +
                             (size_t)lm1 * (BSZ * HSZ);
      const _Float16* hown = h16 + (size_t)prevslot * (LSZ * BSZ * HSZ) +
                             (size_t)l * (BSZ * HSZ);

      // stage one K-chunk (64 halfs/row of both matrices) into buf[bsel]
      auto stage = [&](int kc, int bsel) {
        half8 v[2];
        int   dsoff[2];
#pragma unroll
        for (int it = 0; it < 2; ++it) {
          const int idx = it * NTHR + tid;   // 0..1023 16B-slots
          const int m   = idx >> 9;
          const int rem = idx & 511;
          const int b   = rem >> 3;          // batch row
          const int sl  = rem & 7;           // 16B slot within 128B row-chunk
          const _Float16* rowbase =
              (m == 0) ? ((l == 0) ? x16 + ((size_t)b * TSZ + t) * DSZ
                                   : hin + (size_t)b * HSZ)
                       : hown + (size_t)b * HSZ;
          v[it] = *(const half8*)((const char*)rowbase + kc * 128 + sl * 16);
          dsoff[it] = bsel * BUFB + m * 8192 + b * 128 +
                      ((sl * 16) ^ ((b & 7) << 4));
        }
#pragma unroll
        for (int it = 0; it < 2; ++it)
          *(half8*)(smem + dsoff[it]) = v[it];
      };

      f32x4 acc[4] = {};

      stage(0, 0);
      __syncthreads();

#pragma unroll
      for (int kc = 0; kc < 16; ++kc) {
        const int bsel = kc & 1;
        if (kc < 15) stage(kc + 1, bsel ^ 1);
#pragma unroll
        for (int ksl = 0; ksl < 2; ++ksl) {
#pragma unroll
          for (int mt = 0; mt < 4; ++mt) {
            const int row = mt * 16 + ln15;
            const int off = ksl * 64 + lq * 16;
            const half8 a = *(const half8*)(smem + bsel * BUFB + mat * 8192 +
                                            row * 128 +
                                            (off ^ ((row & 7) << 4)));
            acc[mt] = __builtin_amdgcn_mfma_f32_16x16x32_f16(
                a, bw[kc * 2 + ksl], acc[mt], 0, 0, 0);
          }
        }
        __syncthreads();
      }

      // exchange partials (mat0 + mat1) via zbuf
#pragma unroll
      for (int mt = 0; mt < 4; ++mt)
#pragma unroll
        for (int r = 0; r < 4; ++r) {
          const int b = mt * 16 + lq * 4 + r;     // C/D row = batch
          const int v = rt * 16 + ln15;           // C/D col = gate-row
          zb[(mat * 64 + b) * 68 + v] = acc[mt][r];
        }
      __syncthreads();

      // gate math (fp32), h/c update
#pragma unroll
      for (int e = tid; e < BSZ * 16; e += NTHR) {
        const int b  = e >> 4;
        const int cl = e & 15;
        const int bb = l * 4096 + c0 + cl;
        float zi = zb[b * 68 + 0 * 16 + cl] + zb[(64 + b) * 68 + 0 * 16 + cl] +
                   bih[bb + 0 * 1024] + bhh[bb + 0 * 1024];
        float zf = zb[b * 68 + 1 * 16 + cl] + zb[(64 + b) * 68 + 1 * 16 + cl] +
                   bih[bb + 1 * 1024] + bhh[bb + 1 * 1024];
        float zg = zb[b * 68 + 2 * 16 + cl] + zb[(64 + b) * 68 + 2 * 16 + cl] +
                   bih[bb + 2 * 1024] + bhh[bb + 2 * 1024];
        float zo = zb[b * 68 + 3 * 16 + cl] + zb[(64 + b) * 68 + 3 * 16 + cl] +
                   bih[bb + 3 * 1024] + bhh[bb + 3 * 1024];
        const size_t ci = (size_t)l * (BSZ * HSZ) + (size_t)b * HSZ + c0 + cl;
        float cold = c32[ci];
        float cn = sigmoidf_(zf) * cold + sigmoidf_(zi) * tanhf(zg);
        float hn = sigmoidf_(zo) * tanhf(cn);
        c32[ci] = cn;
        h16[(size_t)(s & 1) * (LSZ * BSZ * HSZ) + ci] = (_Float16)hn;
        if (l == LSZ - 1) out[(size_t)b * HSZ + c0 + cl] = hn;
      }
    }
    grid_barrier(bar, bar + 1);
  }
}

extern "C" void kernel_launch(void* const* d_in, const int* in_sizes, int n_in,
                              void* d_out, int out_size, void* d_ws, size_t ws_size,
                              hipStream_t stream) {
  const float* x   = (const float*)d_in[0];
  const float* Wih = (const float*)d_in[1];
  const float* Whh = (const float*)d_in[2];
  const float* bih = (const float*)d_in[3];
  const float* bhh = (const float*)d_in[4];
  float* out = (float*)d_out;
  char*  ws  = (char*)d_ws;

  // barrier state must be zeroed every call (ws poisoned once to 0xAA)
  hipMemsetAsync(ws + OFF_BAR, 0, 256, stream);

  void* args[] = {(void*)&x, (void*)&Wih, (void*)&Whh, (void*)&bih,
                  (void*)&bhh, (void*)&out, (void*)&ws};
  hipLaunchCooperativeKernel((const void*)lstm_persistent, dim3(NBLK), dim3(NTHR),
                             args, 0, stream);
}

// Round 4
// 21677.771 us; speedup vs baseline: 1.7764x; 1.1792x over previous
//
#include <hip/hip_runtime.h>
#include <math.h>

// ---------------------------------------------------------------------------
// 4-layer LSTM, B=64 T=512 D=H=1024. Persistent cooperative kernel, wavefront
// schedule (layer l works on t = s - l). Round-4 changes vs round-3:
//   - Distributed grid barrier: per-block release flags (64B-spaced) +
//     aggregator block 0 + gen publish. Replaces 256 serialized far-atomic
//     RMWs (~40-50us/step) with parallel flag stores/polls (~2us).
//   - Software-pipelined activation staging: K-chunks of 128 halfs, register
//     slots with distance-2 prefetch (loads for kc+2 issued at top of iter kc,
//     ds_written at end of iter kc+1). 9 syncthreads/step instead of 17.
//   - c-state in registers (block-private), biases hoisted, LDS offsets
//     precomputed.
// Unchanged (round-3-verified): weights-in-VGPR (bw[32] half8/wave), MFMA
// fragment conventions, XOR bank swizzle (byte ^= (row&7)<<4) on ds write+read,
// zbuf exchange, fp32 gate math, h16 double-buffer parity.
// ---------------------------------------------------------------------------

#define BSZ 64
#define TSZ 512
#define DSZ 1024
#define HSZ 1024
#define LSZ 4
#define NBLK 256
#define NTHR 512
#define NSTEP (TSZ + LSZ - 1)   // 515
#define KC_N 8                   // K-chunks of 128 halfs (256 B per row)
#define BUFB 32768               // bytes per LDS activation buffer

typedef _Float16 half8 __attribute__((ext_vector_type(8)));
typedef _Float16 half4 __attribute__((ext_vector_type(4)));
typedef float    f32x4 __attribute__((ext_vector_type(4)));
typedef float    f32x8 __attribute__((ext_vector_type(8)));

// workspace layout (bytes)
constexpr size_t N_X  = (size_t)BSZ * TSZ * DSZ;       // halfs
constexpr size_t N_H  = (size_t)2 * LSZ * BSZ * HSZ;   // halfs (h double buffer)
constexpr size_t OFF_X     = 0;
constexpr size_t OFF_H     = OFF_X + N_X * 2;
constexpr size_t OFF_FLAGS = OFF_H + N_H * 2;          // 256 flags, 64B apart
constexpr size_t OFF_GEN   = OFF_FLAGS + (size_t)NBLK * 64;
constexpr size_t BAR_BYTES = (size_t)NBLK * 64 + 64;

__device__ inline float sigmoidf_(float x) { return 1.0f / (1.0f + expf(-x)); }

// Distributed grid barrier. tgt increases monotonically (1, 2, 3, ...).
// Block b!=0: release-store flags[b]=tgt, spin-acquire on gen.
// Block 0: threads 1..255 spin-acquire flags[1..255], then tid0 publishes gen.
// Transitive h-visibility: writer stores -> syncthreads -> fence -> flag
// release -> block-0 acquire -> syncthreads -> fence -> gen release ->
// spinner acquire (agent-acquire also invalidates stale L1/L2 lines; same
// primitive that rounds 1/3 relied on, validated).
__device__ inline void gbar(unsigned* flags, unsigned* gen, unsigned tgt) {
  __syncthreads();
  if (blockIdx.x == 0) {
    const int t = threadIdx.x;
    if (t >= 1 && t < NBLK) {
      while (__hip_atomic_load(&flags[t * 16], __ATOMIC_ACQUIRE,
                               __HIP_MEMORY_SCOPE_AGENT) < tgt)
        __builtin_amdgcn_s_sleep(1);
    }
    __syncthreads();
    if (t == 0) {
      __threadfence();
      __hip_atomic_store(gen, tgt, __ATOMIC_RELEASE, __HIP_MEMORY_SCOPE_AGENT);
    }
  } else {
    if (threadIdx.x == 0) {
      __threadfence();
      __hip_atomic_store(&flags[(size_t)blockIdx.x * 16], tgt, __ATOMIC_RELEASE,
                         __HIP_MEMORY_SCOPE_AGENT);
      while (__hip_atomic_load(gen, __ATOMIC_ACQUIRE,
                               __HIP_MEMORY_SCOPE_AGENT) < tgt)
        __builtin_amdgcn_s_sleep(1);
    }
    __syncthreads();
  }
}

__global__ __launch_bounds__(NTHR, 2) void lstm_persistent(
    const float* __restrict__ xin, const float* __restrict__ Wih,
    const float* __restrict__ Whh, const float* __restrict__ bih,
    const float* __restrict__ bhh, float* __restrict__ out,
    char* __restrict__ ws)
{
  _Float16* x16   = (_Float16*)(ws + OFF_X);
  _Float16* h16   = (_Float16*)(ws + OFF_H);
  unsigned* flags = (unsigned*)(ws + OFF_FLAGS);
  unsigned* gen   = (unsigned*)(ws + OFF_GEN);

  const int tid  = threadIdx.x;
  const int gtid = blockIdx.x * NTHR + tid;
  const int lane = tid & 63;
  const int w    = tid >> 6;        // wave 0..7
  const int mat  = w >> 2;          // 0 = input-side, 1 = recurrent
  const int rt   = w & 3;           // gate (row-tile of 16 weight rows)
  const int ln15 = lane & 15;
  const int lq   = lane >> 4;

  const int l  = blockIdx.x >> 6;   // layer
  const int cc = blockIdx.x & 63;   // column chunk (16 H-cols)
  const int c0 = cc * 16;

  // ---- weight preload into registers (fp32 -> fp16, one time) ----
  // B-frag (round-3-verified): lane holds W[row = gate rt, col c0+ln15]
  // at k = ks*32 + lq*8 + 0..7.
  const float* Wsel = mat ? Whh : Wih;
  half8 bw[32];
  {
    const int grow = l * 4096 + rt * 1024 + c0 + ln15;
    const float* wrow = Wsel + (size_t)grow * 1024;
#pragma unroll
    for (int ks = 0; ks < 32; ++ks) {
      f32x8 f = *(const f32x8*)(wrow + ks * 32 + lq * 8);
      bw[ks] = __builtin_convertvector(f, half8);
    }
  }

  // ---- hoisted gate biases (step-invariant): my 2 gate-math elements ----
  float bs[2][4];
#pragma unroll
  for (int q = 0; q < 2; ++q) {
    const int e  = tid + q * NTHR;          // 0..1023
    const int cl = e & 15;
    const int bb = l * 4096 + c0 + cl;
#pragma unroll
    for (int g = 0; g < 4; ++g)
      bs[q][g] = bih[bb + g * 1024] + bhh[bb + g * 1024];
  }
  float creg[2] = {0.f, 0.f};               // block-private c-state

  // ---- precomputed staging decomposition (step-invariant) ----
  int st_m[4], st_b[4], st_sl[4], st_ds[4];
#pragma unroll
  for (int it = 0; it < 4; ++it) {
    const int idx = it * NTHR + tid;        // 0..2047 16B-slots
    st_m[it]  = idx >> 10;
    st_b[it]  = (idx & 1023) >> 4;
    st_sl[it] = idx & 15;
    st_ds[it] = st_m[it] * 16384 + st_b[it] * 256 +
                ((st_sl[it] * 16) ^ ((st_b[it] & 7) << 4));
  }

  // ---- pre-phase: cast x to fp16, zero h (both slots) ----
  {
    const f32x4* s4 = (const f32x4*)xin;
    half4*       d4 = (half4*)x16;
    for (int i = gtid; i < (int)(N_X / 4); i += NBLK * NTHR)
      d4[i] = __builtin_convertvector(s4[i], half4);
    f32x4 zz = {0.f, 0.f, 0.f, 0.f};
    f32x4* hz = (f32x4*)h16;
    for (int i = gtid; i < (int)(N_H / 8); i += NBLK * NTHR) hz[i] = zz;
  }
  unsigned btgt = 1;
  gbar(flags, gen, btgt++);

  // ---- LDS: 2 activation buffers (32 KB each) + overlaid zbuf ----
  // buf k at smem + k*BUFB: [2 mats][64 rows][128 halfs(256B)], XOR-swizzled.
  // zbuf f32[2][64][68] (34816 B) overlays buffers after final compute sync.
  __shared__ __align__(16) char smem[2 * BUFB];
  float* zb = (float*)smem;

  const int lm1 = (l > 0) ? (l - 1) : 0;

  for (int s = 0; s < NSTEP; ++s) {
    const int t = s - l;
    if (t >= 0 && t < TSZ) {
      const int prevslot = (s + 1) & 1;
      const _Float16* hin  = h16 + (size_t)prevslot * (LSZ * BSZ * HSZ) +
                             (size_t)lm1 * (BSZ * HSZ);
      const _Float16* hown = h16 + (size_t)prevslot * (LSZ * BSZ * HSZ) +
                             (size_t)l * (BSZ * HSZ);
      const _Float16* base0 = (l == 0) ? x16 + (size_t)t * DSZ : hin;
      const size_t    str0  = (l == 0) ? (size_t)TSZ * DSZ : (size_t)HSZ;

      auto stage_load = [&](int kc, half8 (&v)[4]) {
#pragma unroll
        for (int it = 0; it < 4; ++it) {
          const _Float16* rb = st_m[it] ? hown + (size_t)st_b[it] * HSZ
                                        : base0 + (size_t)st_b[it] * str0;
          v[it] = *(const half8*)((const char*)rb + kc * 256 + st_sl[it] * 16);
        }
      };
      auto stage_write = [&](half8 (&v)[4], int bsel) {
#pragma unroll
        for (int it = 0; it < 4; ++it)
          *(half8*)(smem + bsel * BUFB + st_ds[it]) = v[it];
      };

      f32x4 acc[4] = {};
      half8 vs[2][4];

      stage_load(0, vs[0]);
      stage_load(1, vs[1]);
      stage_write(vs[0], 0);      // compiler waits only vs[0]'s loads (vmcnt(4))
      __syncthreads();

#pragma unroll
      for (int kc = 0; kc < KC_N; ++kc) {
        if (kc + 2 < KC_N) stage_load(kc + 2, vs[kc & 1]);
        // compute on buf[kc&1] (chunk kc)
#pragma unroll
        for (int ksl = 0; ksl < 4; ++ksl) {
#pragma unroll
          for (int mt = 0; mt < 4; ++mt) {
            const int row = mt * 16 + ln15;
            const int off = ksl * 64 + lq * 16;
            const half8 a = *(const half8*)(smem + (kc & 1) * BUFB +
                                            mat * 16384 + row * 256 +
                                            (off ^ ((row & 7) << 4)));
            acc[mt] = __builtin_amdgcn_mfma_f32_16x16x32_f16(
                a, bw[kc * 4 + ksl], acc[mt], 0, 0, 0);
          }
        }
        if (kc + 1 < KC_N) stage_write(vs[(kc + 1) & 1], (kc + 1) & 1);
        __syncthreads();
      }

      // exchange partials (mat0 + mat1) via zbuf
#pragma unroll
      for (int mt = 0; mt < 4; ++mt)
#pragma unroll
        for (int r = 0; r < 4; ++r) {
          const int b = mt * 16 + lq * 4 + r;     // C/D row = batch
          const int v = rt * 16 + ln15;           // C/D col = gate-row
          zb[(mat * 64 + b) * 68 + v] = acc[mt][r];
        }
      __syncthreads();

      // gate math (fp32), h/c update; c and biases in registers
#pragma unroll
      for (int q = 0; q < 2; ++q) {
        const int e  = tid + q * NTHR;
        const int b  = e >> 4;
        const int cl = e & 15;
        float zi = zb[b * 68 + 0 * 16 + cl] + zb[(64 + b) * 68 + 0 * 16 + cl] + bs[q][0];
        float zf = zb[b * 68 + 1 * 16 + cl] + zb[(64 + b) * 68 + 1 * 16 + cl] + bs[q][1];
        float zg = zb[b * 68 + 2 * 16 + cl] + zb[(64 + b) * 68 + 2 * 16 + cl] + bs[q][2];
        float zo = zb[b * 68 + 3 * 16 + cl] + zb[(64 + b) * 68 + 3 * 16 + cl] + bs[q][3];
        float cn = sigmoidf_(zf) * creg[q] + sigmoidf_(zi) * tanhf(zg);
        float hn = sigmoidf_(zo) * tanhf(cn);
        creg[q] = cn;
        h16[(size_t)(s & 1) * (LSZ * BSZ * HSZ) + (size_t)l * (BSZ * HSZ) +
            (size_t)b * HSZ + c0 + cl] = (_Float16)hn;
        if (l == LSZ - 1) out[(size_t)b * HSZ + c0 + cl] = hn;
      }
    }
    gbar(flags, gen, btgt++);
  }
}

extern "C" void kernel_launch(void* const* d_in, const int* in_sizes, int n_in,
                              void* d_out, int out_size, void* d_ws, size_t ws_size,
                              hipStream_t stream) {
  const float* x   = (const float*)d_in[0];
  const float* Wih = (const float*)d_in[1];
  const float* Whh = (const float*)d_in[2];
  const float* bih = (const float*)d_in[3];
  const float* bhh = (const float*)d_in[4];
  float* out = (float*)d_out;
  char*  ws  = (char*)d_ws;

  // barrier flags/gen must be zeroed every call (captured in the graph, so
  // every replay re-zeros before the kernel runs)
  hipMemsetAsync(ws + OFF_FLAGS, 0, BAR_BYTES, stream);

  void* args[] = {(void*)&x, (void*)&Wih, (void*)&Whh, (void*)&bih,
                  (void*)&bhh, (void*)&out, (void*)&ws};
  hipLaunchCooperativeKernel((const void*)lstm_persistent, dim3(NBLK), dim3(NTHR),
                             args, 0, stream);
}

// Round 5
// 5387.300 us; speedup vs baseline: 7.1481x; 4.0239x over previous
//
#include <hip/hip_runtime.h>
#include <math.h>

// ---------------------------------------------------------------------------
// 4-layer LSTM, B=64 T=512 D=H=1024. Persistent cooperative kernel, wavefront
// schedule (layer l works on t = s - l). Round-5 change: remove the per-poll
// L2 cache-maintenance storm.
//   - Spin loops use RELAXED agent atomic loads (plain sc1 loads, no
//     buffer_inv per iteration); ONE acquire fence after spin exit.
//   - No __threadfence / release stores in the loop. All cross-block global
//     writes (h-state, x16 cast, h zero-init) are RELAXED agent atomic
//     stores: write-through to L3, L2 never holds them dirty, so no wbl2 is
//     ever needed. __syncthreads (compiler drains vmcnt before s_barrier)
//     orders them before the flag store.
//   - out[] written only at t == TSZ-1.
//   - Gate math: 2 adjacent columns per thread -> h written as one packed
//     u32 relaxed atomic store.
// Unchanged (round-3/4-verified): weights-in-VGPR (bw[32] half8/wave), MFMA
// fragment conventions, XOR bank swizzle on LDS write+read, distance-2
// staged double-buffer pipeline, zbuf exchange, fp32 gate math.
// ---------------------------------------------------------------------------

#define BSZ 64
#define TSZ 512
#define DSZ 1024
#define HSZ 1024
#define LSZ 4
#define NBLK 256
#define NTHR 512
#define NSTEP (TSZ + LSZ - 1)   // 515
#define KC_N 8                   // K-chunks of 128 halfs (256 B per row)
#define BUFB 32768               // bytes per LDS activation buffer

typedef _Float16 half8  __attribute__((ext_vector_type(8)));
typedef _Float16 half4  __attribute__((ext_vector_type(4)));
typedef _Float16 half2v __attribute__((ext_vector_type(2)));
typedef float    f32x2  __attribute__((ext_vector_type(2)));
typedef float    f32x4  __attribute__((ext_vector_type(4)));
typedef float    f32x8  __attribute__((ext_vector_type(8)));

// workspace layout (bytes)
constexpr size_t N_X  = (size_t)BSZ * TSZ * DSZ;       // halfs
constexpr size_t N_H  = (size_t)2 * LSZ * BSZ * HSZ;   // halfs (h double buffer)
constexpr size_t OFF_X     = 0;
constexpr size_t OFF_H     = OFF_X + N_X * 2;
constexpr size_t OFF_FLAGS = OFF_H + N_H * 2;          // 256 flags, 64B apart
constexpr size_t OFF_GEN   = OFF_FLAGS + (size_t)NBLK * 64;
constexpr size_t BAR_BYTES = (size_t)NBLK * 64 + 64;

__device__ inline float sigmoidf_(float x) { return 1.0f / (1.0f + expf(-x)); }

// Grid barrier, coherence-light version.
// Producers: (entry __syncthreads drains each thread's stores) -> tid0 does a
// RELAXED flag store (write-through). Block 0: threads 1..255 RELAXED-poll the
// 255 flags in parallel, then tid0 RELAXED-stores gen. Spinners RELAXED-poll
// gen; on exit ONE acquire fence (buffer_inv) per block makes L3-fresh data
// visible; trailing __syncthreads covers the block.
__device__ inline void gbar(unsigned* flags, unsigned* gen, unsigned tgt) {
  __syncthreads();
  if (blockIdx.x == 0) {
    const int t = threadIdx.x;
    if (t >= 1 && t < NBLK) {
      while (__hip_atomic_load(&flags[t * 16], __ATOMIC_RELAXED,
                               __HIP_MEMORY_SCOPE_AGENT) < tgt)
        __builtin_amdgcn_s_sleep(2);
    }
    __syncthreads();
    if (t == 0) {
      __hip_atomic_store(gen, tgt, __ATOMIC_RELAXED, __HIP_MEMORY_SCOPE_AGENT);
      __builtin_amdgcn_fence(__ATOMIC_ACQUIRE, "agent");
    }
  } else {
    if (threadIdx.x == 0) {
      __hip_atomic_store(&flags[(size_t)blockIdx.x * 16], tgt, __ATOMIC_RELAXED,
                         __HIP_MEMORY_SCOPE_AGENT);
      while (__hip_atomic_load(gen, __ATOMIC_RELAXED,
                               __HIP_MEMORY_SCOPE_AGENT) < tgt)
        __builtin_amdgcn_s_sleep(2);
      __builtin_amdgcn_fence(__ATOMIC_ACQUIRE, "agent");
    }
  }
  __syncthreads();
}

__global__ __launch_bounds__(NTHR, 2) void lstm_persistent(
    const float* __restrict__ xin, const float* __restrict__ Wih,
    const float* __restrict__ Whh, const float* __restrict__ bih,
    const float* __restrict__ bhh, float* __restrict__ out,
    char* __restrict__ ws)
{
  _Float16* x16   = (_Float16*)(ws + OFF_X);
  _Float16* h16   = (_Float16*)(ws + OFF_H);
  unsigned* flags = (unsigned*)(ws + OFF_FLAGS);
  unsigned* gen   = (unsigned*)(ws + OFF_GEN);

  const int tid  = threadIdx.x;
  const int gtid = blockIdx.x * NTHR + tid;
  const int lane = tid & 63;
  const int w    = tid >> 6;        // wave 0..7
  const int mat  = w >> 2;          // 0 = input-side, 1 = recurrent
  const int rt   = w & 3;           // gate (row-tile of 16 weight rows)
  const int ln15 = lane & 15;
  const int lq   = lane >> 4;

  const int l  = blockIdx.x >> 6;   // layer
  const int cc = blockIdx.x & 63;   // column chunk (16 H-cols)
  const int c0 = cc * 16;

  // ---- weight preload into registers (fp32 -> fp16, one time) ----
  const float* Wsel = mat ? Whh : Wih;
  half8 bw[32];
  {
    const int grow = l * 4096 + rt * 1024 + c0 + ln15;
    const float* wrow = Wsel + (size_t)grow * 1024;
#pragma unroll
    for (int ks = 0; ks < 32; ++ks) {
      f32x8 f = *(const f32x8*)(wrow + ks * 32 + lq * 8);
      bw[ks] = __builtin_convertvector(f, half8);
    }
  }

  // ---- gate-math ownership: 2 adjacent columns of one batch row ----
  const int gb = tid >> 3;            // batch row 0..63
  const int gc = (tid & 7) * 2;       // even col 0..14
  float bsg[4][2];
#pragma unroll
  for (int g = 0; g < 4; ++g) {
    const int bb = l * 4096 + g * 1024 + c0 + gc;
    bsg[g][0] = bih[bb] + bhh[bb];
    bsg[g][1] = bih[bb + 1] + bhh[bb + 1];
  }
  float cr0 = 0.f, cr1 = 0.f;         // block-private c-state (registers)

  // ---- precomputed staging decomposition (step-invariant) ----
  int st_m[4], st_b[4], st_sl[4], st_ds[4];
#pragma unroll
  for (int it = 0; it < 4; ++it) {
    const int idx = it * NTHR + tid;  // 0..2047 16B-slots
    st_m[it]  = idx >> 10;
    st_b[it]  = (idx & 1023) >> 4;
    st_sl[it] = idx & 15;
    st_ds[it] = st_m[it] * 16384 + st_b[it] * 256 +
                ((st_sl[it] * 16) ^ ((st_b[it] & 7) << 4));
  }

  // ---- pre-phase: cast x to fp16, zero h — write-through atomic stores ----
  {
    const f32x4* s4 = (const f32x4*)xin;
    unsigned long long* xu = (unsigned long long*)x16;
    for (int i = gtid; i < (int)(N_X / 4); i += NBLK * NTHR) {
      half4 v = __builtin_convertvector(s4[i], half4);
      __hip_atomic_store(&xu[i], __builtin_bit_cast(unsigned long long, v),
                         __ATOMIC_RELAXED, __HIP_MEMORY_SCOPE_AGENT);
    }
    unsigned long long* hz = (unsigned long long*)h16;
    for (int i = gtid; i < (int)(N_H / 4); i += NBLK * NTHR)
      __hip_atomic_store(&hz[i], 0ull, __ATOMIC_RELAXED,
                         __HIP_MEMORY_SCOPE_AGENT);
  }
  unsigned btgt = 1;
  gbar(flags, gen, btgt++);

  // ---- LDS: 2 activation buffers (32 KB each) + overlaid zbuf ----
  __shared__ __align__(16) char smem[2 * BUFB];
  float* zb = (float*)smem;

  const int lm1 = (l > 0) ? (l - 1) : 0;

  for (int s = 0; s < NSTEP; ++s) {
    const int t = s - l;
    if (t >= 0 && t < TSZ) {
      const int prevslot = (s + 1) & 1;
      const _Float16* hin  = h16 + (size_t)prevslot * (LSZ * BSZ * HSZ) +
                             (size_t)lm1 * (BSZ * HSZ);
      const _Float16* hown = h16 + (size_t)prevslot * (LSZ * BSZ * HSZ) +
                             (size_t)l * (BSZ * HSZ);
      const _Float16* base0 = (l == 0) ? x16 + (size_t)t * DSZ : hin;
      const size_t    str0  = (l == 0) ? (size_t)TSZ * DSZ : (size_t)HSZ;

      auto stage_load = [&](int kc, half8 (&v)[4]) {
#pragma unroll
        for (int it = 0; it < 4; ++it) {
          const _Float16* rb = st_m[it] ? hown + (size_t)st_b[it] * HSZ
                                        : base0 + (size_t)st_b[it] * str0;
          v[it] = *(const half8*)((const char*)rb + kc * 256 + st_sl[it] * 16);
        }
      };
      auto stage_write = [&](half8 (&v)[4], int bsel) {
#pragma unroll
        for (int it = 0; it < 4; ++it)
          *(half8*)(smem + bsel * BUFB + st_ds[it]) = v[it];
      };

      f32x4 acc[4] = {};
      half8 vs[2][4];

      stage_load(0, vs[0]);
      stage_load(1, vs[1]);
      stage_write(vs[0], 0);
      __syncthreads();

#pragma unroll
      for (int kc = 0; kc < KC_N; ++kc) {
        if (kc + 2 < KC_N) stage_load(kc + 2, vs[kc & 1]);
#pragma unroll
        for (int ksl = 0; ksl < 4; ++ksl) {
#pragma unroll
          for (int mt = 0; mt < 4; ++mt) {
            const int row = mt * 16 + ln15;
            const int off = ksl * 64 + lq * 16;
            const half8 a = *(const half8*)(smem + (kc & 1) * BUFB +
                                            mat * 16384 + row * 256 +
                                            (off ^ ((row & 7) << 4)));
            acc[mt] = __builtin_amdgcn_mfma_f32_16x16x32_f16(
                a, bw[kc * 4 + ksl], acc[mt], 0, 0, 0);
          }
        }
        if (kc + 1 < KC_N) stage_write(vs[(kc + 1) & 1], (kc + 1) & 1);
        __syncthreads();
      }

      // exchange partials (mat0 + mat1) via zbuf
#pragma unroll
      for (int mt = 0; mt < 4; ++mt)
#pragma unroll
        for (int r = 0; r < 4; ++r) {
          const int b = mt * 16 + lq * 4 + r;     // C/D row = batch
          const int v = rt * 16 + ln15;           // C/D col = gate-row
          zb[(mat * 64 + b) * 68 + v] = acc[mt][r];
        }
      __syncthreads();

      // gate math (fp32): 2 adjacent columns per thread
      {
        auto zread = [&](int g) -> f32x2 {
          f32x2 a = *(const f32x2*)&zb[gb * 68 + g * 16 + gc];
          f32x2 b2 = *(const f32x2*)&zb[(64 + gb) * 68 + g * 16 + gc];
          return a + b2;
        };
        f32x2 vi = zread(0), vf = zread(1), vg = zread(2), vo = zread(3);
        float cn0 = sigmoidf_(vf[0] + bsg[1][0]) * cr0 +
                    sigmoidf_(vi[0] + bsg[0][0]) * tanhf(vg[0] + bsg[2][0]);
        float cn1 = sigmoidf_(vf[1] + bsg[1][1]) * cr1 +
                    sigmoidf_(vi[1] + bsg[0][1]) * tanhf(vg[1] + bsg[2][1]);
        float hn0 = sigmoidf_(vo[0] + bsg[3][0]) * tanhf(cn0);
        float hn1 = sigmoidf_(vo[1] + bsg[3][1]) * tanhf(cn1);
        cr0 = cn0; cr1 = cn1;
        half2v hv; hv[0] = (_Float16)hn0; hv[1] = (_Float16)hn1;
        const size_t ho = (size_t)(s & 1) * (LSZ * BSZ * HSZ) +
                          (size_t)l * (BSZ * HSZ) + (size_t)gb * HSZ + c0 + gc;
        __hip_atomic_store((unsigned*)(h16 + ho),
                           __builtin_bit_cast(unsigned, hv),
                           __ATOMIC_RELAXED, __HIP_MEMORY_SCOPE_AGENT);
        if (l == LSZ - 1 && t == TSZ - 1) {
          out[(size_t)gb * HSZ + c0 + gc]     = hn0;
          out[(size_t)gb * HSZ + c0 + gc + 1] = hn1;
        }
      }
    }
    gbar(flags, gen, btgt++);
  }
}

extern "C" void kernel_launch(void* const* d_in, const int* in_sizes, int n_in,
                              void* d_out, int out_size, void* d_ws, size_t ws_size,
                              hipStream_t stream) {
  const float* x   = (const float*)d_in[0];
  const float* Wih = (const float*)d_in[1];
  const float* Whh = (const float*)d_in[2];
  const float* bih = (const float*)d_in[3];
  const float* bhh = (const float*)d_in[4];
  float* out = (float*)d_out;
  char*  ws  = (char*)d_ws;

  // barrier flags/gen zeroed every call (captured in the graph -> re-zeroed
  // before the kernel on every replay)
  hipMemsetAsync(ws + OFF_FLAGS, 0, BAR_BYTES, stream);

  void* args[] = {(void*)&x, (void*)&Wih, (void*)&Whh, (void*)&bih,
                  (void*)&bhh, (void*)&out, (void*)&ws};
  hipLaunchCooperativeKernel((const void*)lstm_persistent, dim3(NBLK), dim3(NTHR),
                             args, 0, stream);
}